// Round 6
// baseline (95.676 us; speedup 1.0000x reference)
//
#include <hip/hip_runtime.h>
#include <cstdint>
#include <cstddef>

// LocallyDirected1D: y[b,o] = tanh( sum_{e: out_idx[e]==o} x[b, in_idx[e]] * w[e] + bias[o] )
// out_idx sorted ascending; in_idx == arange in practice (verified per lane; wave-uniform
// clamped-gather fallback otherwise).
//
// R6: exact-once fused design, 2 launches, no atomics, no zero/finish passes.
//  K1 ld1d_bounds: bnd[o] = lower_bound(out_idx, o) (proven R4 kernel).
//  K2 ld1d_fused : block owns OPB=16 consecutive outputs -> contiguous edge range
//    [E0,E1). Each of 4 waves sweeps that range ONCE in 512-edge windows (8 edges/lane)
//    for its own 16 batch rows. Per window: run-structure + scan masks computed once
//    (row-independent); per row: two 7-fma in-lane chains + 6-step masked DPP scan.
//    Emissions (tanh+bias fused) are exactly-once: in-lane mid runs -> t_j; head run ->
//    t0 (+prev-lane scan sp if continued, +carry if o==firsto); tail-run ends (EendT =
//    lane<63 && !cont(next)) -> scanned s (+carry if o==firsto); wave-trailing run ->
//    per-row carry in LDS cyl[wave][row], flushed at window boundaries / range end.
//    Out-of-range lanes of the block's last window join the trailing run with w=0.

constexpr int OPB = 16;    // outputs per block
constexpr int WPB = 4;     // waves per block
constexpr int RPW = 16;    // batch rows per wave
constexpr int EPW = 512;   // edges per window (8 per lane)

#define DPP_SHR1 0x111
#define DPP_SHR2 0x112
#define DPP_SHR4 0x114
#define DPP_SHR8 0x118
#define DPP_BC15 0x142
#define DPP_BC31 0x143

#define SCAN_STEP(S, MF, CTRL, RM)                                                            \
    {                                                                                         \
        int _t = __builtin_amdgcn_update_dpp(0, __float_as_int(S), (CTRL), (RM), 0xF, true);  \
        (S) = fmaf((MF), __int_as_float(_t), (S));                                            \
    }

#define MAXS_STEP(R, CTRL, RM)                                                                \
    {                                                                                         \
        int _t = __builtin_amdgcn_update_dpp(0, (R), (CTRL), (RM), 0xF, true);                \
        (R) = max((R), _t);                                                                   \
    }

// K1: bnd[o] = first e with out_idx[e] >= o, for o in [0, n_out]. Exactly-once writes.
__global__ __launch_bounds__(256)
void ld1d_bounds(const int* __restrict__ out_idx, int* __restrict__ bnd,
                 int nnz, int n_out)
{
    int e = blockIdx.x * 256 + threadIdx.x;
    if (e >= nnz) return;
    int cur  = out_idx[e];
    int prev = (e == 0) ? -1 : out_idx[e - 1];
    for (int o = prev + 1; o <= cur; ++o) bnd[o] = e;
    if (e == nnz - 1)
        for (int o = cur + 1; o <= n_out; ++o) bnd[o] = nnz;
}

__global__ __launch_bounds__(256)
void ld1d_fused(const float* __restrict__ x, const float* __restrict__ wgt,
                const float* __restrict__ bias, const int* __restrict__ in_idx,
                const int* __restrict__ out_idx, const int* __restrict__ bnd,
                float* __restrict__ out,
                int n_in, int nnz, int n_out, int batch)
{
    __shared__ int   sbO[OPB + 1];
    __shared__ float sbias[OPB];
    __shared__ float cyl[WPB][RPW];

    const int tid  = threadIdx.x;
    const int lane = tid & 63;
    const int wv   = tid >> 6;
    const int O0   = blockIdx.x * OPB;
    const int nO   = min(OPB, n_out - O0);

    if (tid <= nO) sbO[tid] = bnd[min(O0 + tid, n_out)];
    if (tid < nO)  sbias[tid] = bias[O0 + tid];
    __syncthreads();

    const int E0 = sbO[0];
    const int E1 = sbO[nO];
    const int b0 = wv * RPW;
    const int nrows = min(RPW, batch - b0);

    if (E1 > E0 && nrows > 0) {
        if (lane < RPW) cyl[wv][lane] = 0.f;
        const int olast = out_idx[E1 - 1];
        const int CB = E0 & ~7;
        int pend = -1;

        for (int c0 = CB; c0 < E1; c0 += EPW) {
            const int e0 = c0 + lane * 8;
            const int nv = E1 - e0;                    // valid edges this lane (may be <=0)

            int iv[8]; int ov[8]; float w[8]; bool fok;
            if (nv >= 8) {
                int4 i0 = *reinterpret_cast<const int4*>(in_idx + e0);
                int4 i1 = *reinterpret_cast<const int4*>(in_idx + e0 + 4);
                int4 o0 = *reinterpret_cast<const int4*>(out_idx + e0);
                int4 o1 = *reinterpret_cast<const int4*>(out_idx + e0 + 4);
                float4 w0 = *reinterpret_cast<const float4*>(wgt + e0);
                float4 w1 = *reinterpret_cast<const float4*>(wgt + e0 + 4);
                iv[0]=i0.x; iv[1]=i0.y; iv[2]=i0.z; iv[3]=i0.w;
                iv[4]=i1.x; iv[5]=i1.y; iv[6]=i1.z; iv[7]=i1.w;
                ov[0]=o0.x; ov[1]=o0.y; ov[2]=o0.z; ov[3]=o0.w;
                ov[4]=o1.x; ov[5]=o1.y; ov[6]=o1.z; ov[7]=o1.w;
                w[0]=w0.x; w[1]=w0.y; w[2]=w0.z; w[3]=w0.w;
                w[4]=w1.x; w[5]=w1.y; w[6]=w1.z; w[7]=w1.w;
                fok = true;
                #pragma unroll
                for (int k = 0; k < 8; ++k) fok = fok && (iv[k] == e0 + k);
            } else if (nv > 0) {
                fok = true;
                #pragma unroll
                for (int k = 0; k < 8; ++k) {
                    int a = min(e0 + k, E1 - 1);
                    iv[k] = in_idx[a]; ov[k] = out_idx[a];
                    if (k < nv) { w[k] = wgt[a]; fok = fok && (iv[k] == e0 + k); }
                    else        { w[k] = 0.f; }
                }
            } else {
                #pragma unroll
                for (int k = 0; k < 8; ++k) { iv[k] = 0; ov[k] = olast; w[k] = 0.f; }
                fok = true;
            }
            const bool fast = (bool)__all((int)fok);

            // In-lane run structure (row-independent).
            bool bb[7]; float u[7];
            #pragma unroll
            for (int k = 0; k < 7; ++k) { bb[k] = (ov[k] != ov[k+1]); u[k] = bb[k] ? 0.f : 1.f; }
            const bool hasB = bb[0]|bb[1]|bb[2]|bb[3]|bb[4]|bb[5]|bb[6];

            const int  pw   = __shfl_up(ov[7], 1);
            const bool cont = (lane > 0) && (ov[0] == pw);
            const int  cnx  = __shfl_down((int)cont, 1);
            const bool EendT = (lane < 63) && (cnx == 0);   // tail run truly ends here
            const bool fbrk = hasB || !cont;

            bool sfx[7];
            sfx[6] = bb[6];
            #pragma unroll
            for (int j = 5; j >= 1; --j) sfx[j] = bb[j] | sfx[j+1];
            bool E[7];
            #pragma unroll
            for (int j = 1; j <= 6; ++j) E[j] = bb[j-1] && sfx[j];

            int r = fbrk ? lane : 0;
            MAXS_STEP(r, DPP_SHR1, 0xF); MAXS_STEP(r, DPP_SHR2, 0xF);
            MAXS_STEP(r, DPP_SHR4, 0xF); MAXS_STEP(r, DPP_SHR8, 0xF);
            MAXS_STEP(r, DPP_BC15, 0xA); MAXS_STEP(r, DPP_BC31, 0xC);
            const float mf1  = (r <= lane - 1) ? 1.f : 0.f;
            const float mf2  = (r <= lane - 2) ? 1.f : 0.f;
            const float mf4  = (r <= lane - 4) ? 1.f : 0.f;
            const float mf8  = (r <= lane - 8) ? 1.f : 0.f;
            const float mf15 = (r <= (lane & ~15) - 1) ? 1.f : 0.f;
            const float mf31 = (r <= 31) ? 1.f : 0.f;

            const int firsto = __builtin_amdgcn_readlane(ov[0], 0);
            const int lasto  = __builtin_amdgcn_readlane(ov[7], 63);
            const bool single = (firsto == lasto);

            // Boundary flush: trailing run closed exactly at the previous window edge.
            if (pend >= 0 && pend != firsto) {
                if ((unsigned)(pend - O0) < (unsigned)nO && lane < nrows)
                    out[(size_t)(b0 + lane) * n_out + pend] =
                        tanhf(cyl[wv][lane] + sbias[pend - O0]);
                if (lane < RPW) cyl[wv][lane] = 0.f;
            }
            pend = lasto;

            const int nmax = n_in - 1;
            int ix[8];
            #pragma unroll
            for (int k = 0; k < 8; ++k) ix[k] = min(max(iv[k], 0), nmax);

            const bool ldv = fast && (nv > 0) && (e0 + 8 <= n_in);  // vector x load ok
            const bool lds_ = fast && (nv > 0) && !(e0 + 8 <= n_in); // clamped scalar x

            float* pbr = out + (size_t)b0 * (size_t)n_out;

            // Per-row processing body.
            auto processRow = [&](const float4& a0, const float4& a1, int i, float* pr) {
                float q0, q1, q2, q3, q4, q5, q6, q7;
                q0 = a0.x * w[0]; q1 = a0.y * w[1]; q2 = a0.z * w[2]; q3 = a0.w * w[3];
                q4 = a1.x * w[4]; q5 = a1.y * w[5]; q6 = a1.z * w[6]; q7 = a1.w * w[7];
                const float cy = cyl[wv][i];
                float t6 = fmaf(u[6], q7, q6);
                float t5 = fmaf(u[5], t6, q5);
                float t4 = fmaf(u[4], t5, q4);
                float t3 = fmaf(u[3], t4, q3);
                float t2 = fmaf(u[2], t3, q2);
                float t1 = fmaf(u[1], t2, q1);
                float t0 = fmaf(u[0], t1, q0);
                float s = q0;
                s = fmaf(u[0], s, q1); s = fmaf(u[1], s, q2); s = fmaf(u[2], s, q3);
                s = fmaf(u[3], s, q4); s = fmaf(u[4], s, q5); s = fmaf(u[5], s, q6);
                s = fmaf(u[6], s, q7);
                SCAN_STEP(s, mf1,  DPP_SHR1, 0xF);
                SCAN_STEP(s, mf2,  DPP_SHR2, 0xF);
                SCAN_STEP(s, mf4,  DPP_SHR4, 0xF);
                SCAN_STEP(s, mf8,  DPP_SHR8, 0xF);
                SCAN_STEP(s, mf15, DPP_BC15, 0xA);
                SCAN_STEP(s, mf31, DPP_BC31, 0xC);
                const float sp = __shfl_up(s, 1);
                if (EendT) {
                    const int o = ov[7];
                    if ((unsigned)(o - O0) < (unsigned)nO) {
                        float v = s + ((o == firsto) ? cy : 0.f);
                        pr[o] = tanhf(v + sbias[o - O0]);
                    }
                }
                if (hasB) {
                    const int o = ov[0];
                    if ((unsigned)(o - O0) < (unsigned)nO) {
                        float v = t0;
                        if (cont) v += sp;
                        if (o == firsto) v += cy;
                        pr[o] = tanhf(v + sbias[o - O0]);
                    }
                }
                if (E[1] && (unsigned)(ov[1]-O0) < (unsigned)nO) pr[ov[1]] = tanhf(t1 + sbias[ov[1]-O0]);
                if (E[2] && (unsigned)(ov[2]-O0) < (unsigned)nO) pr[ov[2]] = tanhf(t2 + sbias[ov[2]-O0]);
                if (E[3] && (unsigned)(ov[3]-O0) < (unsigned)nO) pr[ov[3]] = tanhf(t3 + sbias[ov[3]-O0]);
                if (E[4] && (unsigned)(ov[4]-O0) < (unsigned)nO) pr[ov[4]] = tanhf(t4 + sbias[ov[4]-O0]);
                if (E[5] && (unsigned)(ov[5]-O0) < (unsigned)nO) pr[ov[5]] = tanhf(t5 + sbias[ov[5]-O0]);
                if (E[6] && (unsigned)(ov[6]-O0) < (unsigned)nO) pr[ov[6]] = tanhf(t6 + sbias[ov[6]-O0]);
                float cyn = __int_as_float(__builtin_amdgcn_readlane(__float_as_int(s), 63));
                if (single) cyn += cy;
                if (lane == 0) cyl[wv][i] = cyn;
            };

            const float4 Z4 = make_float4(0.f, 0.f, 0.f, 0.f);
            auto loadRow = [&](int i, float4& a0, float4& a1) {
                if (ldv) {
                    const float* p = x + (size_t)(b0 + i) * (size_t)n_in + e0;
                    a0 = *reinterpret_cast<const float4*>(p);
                    a1 = *reinterpret_cast<const float4*>(p + 4);
                } else if (lds_) {
                    const float* p = x + (size_t)(b0 + i) * (size_t)n_in;
                    a0 = make_float4(p[ix[0]], p[ix[1]], p[ix[2]], p[ix[3]]);
                    a1 = make_float4(p[ix[4]], p[ix[5]], p[ix[6]], p[ix[7]]);
                } else {
                    a0 = Z4; a1 = Z4;
                }
            };

            if (fast) {
                // 2-row double-buffered pipeline.
                const int nb2 = nrows >> 1;
                float4 ca0, ca1, cb0, cb1;
                if (nb2 > 0) { loadRow(0, ca0, ca1); loadRow(1, cb0, cb1); }
                for (int ib = 0; ib < nb2; ++ib) {
                    float4 na0, na1, nb0_, nb1_;
                    const bool more = (2*ib + 2) < nrows;
                    if (more) {
                        loadRow(2*ib + 2, na0, na1);
                        if (2*ib + 3 < nrows) loadRow(2*ib + 3, nb0_, nb1_);
                        else { nb0_ = Z4; nb1_ = Z4; }
                    }
                    processRow(ca0, ca1, 2*ib,     pbr + (size_t)(2*ib) * n_out);
                    processRow(cb0, cb1, 2*ib + 1, pbr + (size_t)(2*ib + 1) * n_out);
                    if (more) { ca0 = na0; ca1 = na1; cb0 = nb0_; cb1 = nb1_; }
                }
                if (nrows & 1) {
                    float4 a0, a1;
                    loadRow(nrows - 1, a0, a1);
                    processRow(a0, a1, nrows - 1, pbr + (size_t)(nrows - 1) * n_out);
                }
            } else {
                // Gather fallback (wave-uniform; in_idx not identity here).
                for (int i = 0; i < nrows; ++i) {
                    const float* p = x + (size_t)(b0 + i) * (size_t)n_in;
                    float4 a0 = make_float4(p[ix[0]], p[ix[1]], p[ix[2]], p[ix[3]]);
                    float4 a1 = make_float4(p[ix[4]], p[ix[5]], p[ix[6]], p[ix[7]]);
                    if (nv <= 0) { a0 = Z4; a1 = Z4; }
                    processRow(a0, a1, i, pbr + (size_t)i * n_out);
                }
            }
        }

        // Final flush of the trailing run.
        if (pend >= 0 && (unsigned)(pend - O0) < (unsigned)nO && lane < nrows)
            out[(size_t)(b0 + lane) * n_out + pend] =
                tanhf(cyl[wv][lane] + sbias[pend - O0]);
    }

    // Outputs with zero edges: y = tanh(bias).
    if (nrows > 0) {
        for (int k = 0; k < nO; ++k) {
            if (sbO[k] == sbO[k + 1]) {
                if (lane < nrows)
                    out[(size_t)(b0 + lane) * n_out + (O0 + k)] = tanhf(sbias[k]);
            }
        }
    }
}

extern "C" void kernel_launch(void* const* d_in, const int* in_sizes, int n_in_arrs,
                              void* d_out, int out_size, void* d_ws, size_t ws_size,
                              hipStream_t stream)
{
    const float* x       = (const float*)d_in[0];
    const float* wgt     = (const float*)d_in[1];
    const float* bias    = (const float*)d_in[2];
    const int*   in_idx  = (const int*)d_in[3];
    const int*   out_idx = (const int*)d_in[4];
    float*       out     = (float*)d_out;
    int*         bnd     = (int*)d_ws;                 // (n_out+1) ints

    const int nnz   = in_sizes[1];
    const int n_out = in_sizes[2];           // N_OUT * FILTERS(=1)
    const int batch = out_size / n_out;      // 64
    const int n_in  = in_sizes[0] / batch;   // 1,000,000

    hipLaunchKernelGGL(ld1d_bounds, dim3((nnz + 255) / 256), dim3(256), 0, stream,
                       out_idx, bnd, nnz, n_out);

    const int blocks = (n_out + OPB - 1) / OPB;
    hipLaunchKernelGGL(ld1d_fused, dim3(blocks), dim3(256), 0, stream,
                       x, wgt, bias, in_idx, out_idx, bnd, out,
                       n_in, nnz, n_out, batch);
}

// Round 8
// 74.881 us; speedup vs baseline: 1.2777x; 1.2777x over previous
//
#include <hip/hip_runtime.h>
#include <cstdint>
#include <cstddef>

// LocallyDirected1D: y[b,o] = tanh( sum_{e: out_idx[e]==o} x[b, in_idx[e]] * w[e] + bias[o] )
// out_idx sorted ascending; in_idx == arange in practice (verified per lane; wave-uniform
// clamped-gather fallback otherwise).
//
// R8 = R5 (proven) with two minimal deltas in the accum fast path only:
//  * 4-row batches with next-batch register prefetch (16 float4 in flight vs 8)
//  * non-temporal x loads (x is read exactly once -> don't pollute L2; metadata and
//    atomic RMW traffic keep the cache)
// Engine (EPW=512, 8 edges/lane, two 7-fma in-lane chains, 6-step masked DPP wave scan,
// atomic emissions, zero/finish kernels) is byte-identical to R5.

constexpr int EPW = 512;   // edges per window (8 per lane)
constexpr int RPW = 16;    // batch rows per wave (4 waves share a window)
constexpr int WPB = 4;     // waves per block

#define DPP_SHR1 0x111
#define DPP_SHR2 0x112
#define DPP_SHR4 0x114
#define DPP_SHR8 0x118
#define DPP_BC15 0x142
#define DPP_BC31 0x143

#define SCAN_STEP(S, MF, CTRL, RM)                                                            \
    {                                                                                         \
        int _t = __builtin_amdgcn_update_dpp(0, __float_as_int(S), (CTRL), (RM), 0xF, true);  \
        (S) = fmaf((MF), __int_as_float(_t), (S));                                            \
    }

#define MAXS_STEP(R, CTRL, RM)                                                                \
    {                                                                                         \
        int _t = __builtin_amdgcn_update_dpp(0, (R), (CTRL), (RM), 0xF, true);                \
        (R) = max((R), _t);                                                                   \
    }

typedef float __attribute__((ext_vector_type(4))) f4v;

__device__ __forceinline__ float4 ntload4(const float* p) {
    f4v v = __builtin_nontemporal_load(reinterpret_cast<const f4v*>(p));
    return make_float4(v.x, v.y, v.z, v.w);
}

__device__ __forceinline__ void atomAddF(float* p, float v) {
    __hip_atomic_fetch_add(p, v, __ATOMIC_RELAXED, __HIP_MEMORY_SCOPE_AGENT);
}

__global__ __launch_bounds__(256)
void ld1d_zero(float* __restrict__ p, int n4, int ntot)
{
    int i = blockIdx.x * 256 + threadIdx.x;
    if (i < n4)
        *reinterpret_cast<float4*>(p + (size_t)i * 4) = make_float4(0.f, 0.f, 0.f, 0.f);
    if (blockIdx.x == 0 && threadIdx.x == 0)
        for (int k = n4 * 4; k < ntot; ++k) p[k] = 0.f;
}

__global__ __launch_bounds__(256)
void ld1d_accum(const float* __restrict__ x, const float* __restrict__ wgt,
                const int* __restrict__ in_idx, const int* __restrict__ out_idx,
                float* __restrict__ pre, int n_in, int nnz, int n_out, int batch, int wpw)
{
    const int lane = threadIdx.x & 63;
    const int gw   = blockIdx.x * WPB + (threadIdx.x >> 6);
    const int wid  = gw / wpw;
    const long long c0l = (long long)wid * EPW;
    if (c0l >= (long long)nnz) return;
    const int b0 = (gw - wid * wpw) * RPW;
    const int nrows = min(RPW, batch - b0);
    if (nrows <= 0) return;

    const int e0   = (int)c0l + lane * 8;
    const int last = nnz - 1;

    int   iv[8]; int ov[8]; float w[8];
    bool fok;
    if (e0 + 7 < nnz) {
        int4 i0 = *reinterpret_cast<const int4*>(in_idx + e0);
        int4 i1 = *reinterpret_cast<const int4*>(in_idx + e0 + 4);
        int4 o0 = *reinterpret_cast<const int4*>(out_idx + e0);
        int4 o1 = *reinterpret_cast<const int4*>(out_idx + e0 + 4);
        float4 w0 = *reinterpret_cast<const float4*>(wgt + e0);
        float4 w1 = *reinterpret_cast<const float4*>(wgt + e0 + 4);
        iv[0]=i0.x; iv[1]=i0.y; iv[2]=i0.z; iv[3]=i0.w; iv[4]=i1.x; iv[5]=i1.y; iv[6]=i1.z; iv[7]=i1.w;
        ov[0]=o0.x; ov[1]=o0.y; ov[2]=o0.z; ov[3]=o0.w; ov[4]=o1.x; ov[5]=o1.y; ov[6]=o1.z; ov[7]=o1.w;
        w[0]=w0.x; w[1]=w0.y; w[2]=w0.z; w[3]=w0.w; w[4]=w1.x; w[5]=w1.y; w[6]=w1.z; w[7]=w1.w;
        fok = true;
        #pragma unroll
        for (int k = 0; k < 8; ++k) fok = fok && (iv[k] == e0 + k);
    } else if (e0 < nnz) {
        #pragma unroll
        for (int k = 0; k < 8; ++k) {
            int a = min(e0 + k, last);
            iv[k] = in_idx[a]; ov[k] = out_idx[a];
            w[k]  = (e0 + k < nnz) ? wgt[a] : 0.f;
        }
        fok = false;
    } else {
        int o = out_idx[last];
        #pragma unroll
        for (int k = 0; k < 8; ++k) { iv[k] = 0; ov[k] = o; w[k] = 0.f; }
        fok = true;
    }
    const bool fast = (bool)__all((int)fok);

    // In-lane run structure (row-independent).
    bool bb[7]; float u[7];
    #pragma unroll
    for (int k = 0; k < 7; ++k) { bb[k] = (ov[k] != ov[k + 1]); u[k] = bb[k] ? 0.f : 1.f; }
    const bool hasB = bb[0] | bb[1] | bb[2] | bb[3] | bb[4] | bb[5] | bb[6];

    const int  pw   = __shfl_up(ov[7], 1);
    const bool cont = (lane > 0) && (ov[0] == pw);
    const bool fbrk = hasB || !cont;
    const int  fnext = __shfl_down((int)fbrk, 1);
    const bool Eend  = (lane == 63) || (fnext != 0);

    bool sfx[7];
    sfx[6] = bb[6];
    #pragma unroll
    for (int j = 5; j >= 1; --j) sfx[j] = bb[j] | sfx[j + 1];
    bool E[7];
    #pragma unroll
    for (int j = 1; j <= 6; ++j) E[j] = bb[j - 1] && sfx[j];
    const bool anyMid = (bool)__any((int)(E[1] | E[2] | E[3] | E[4] | E[5] | E[6]));

    // Run-start lane r -> per-step scan masks.
    int r = fbrk ? lane : 0;
    MAXS_STEP(r, DPP_SHR1, 0xF); MAXS_STEP(r, DPP_SHR2, 0xF);
    MAXS_STEP(r, DPP_SHR4, 0xF); MAXS_STEP(r, DPP_SHR8, 0xF);
    MAXS_STEP(r, DPP_BC15, 0xA); MAXS_STEP(r, DPP_BC31, 0xC);
    const float mf1  = (r <= lane - 1) ? 1.f : 0.f;
    const float mf2  = (r <= lane - 2) ? 1.f : 0.f;
    const float mf4  = (r <= lane - 4) ? 1.f : 0.f;
    const float mf8  = (r <= lane - 8) ? 1.f : 0.f;
    const float mf15 = (r <= (lane & ~15) - 1) ? 1.f : 0.f;
    const float mf31 = (r <= 31) ? 1.f : 0.f;

    // Clamped gather indices (slow path).
    const int nmax = n_in - 1;
    int ix[8];
    #pragma unroll
    for (int k = 0; k < 8; ++k) ix[k] = min(max(iv[k], 0), nmax);

    float* pb = pre + (size_t)b0 * (size_t)n_out;

    auto processRow = [&](const float q[8], float* pbr) {
        float t7 = q[7];
        float t6 = fmaf(u[6], t7, q[6]);
        float t5 = fmaf(u[5], t6, q[5]);
        float t4 = fmaf(u[4], t5, q[4]);
        float t3 = fmaf(u[3], t4, q[3]);
        float t2 = fmaf(u[2], t3, q[2]);
        float t1 = fmaf(u[1], t2, q[1]);
        float t0 = fmaf(u[0], t1, q[0]);
        float s = q[0];
        s = fmaf(u[0], s, q[1]); s = fmaf(u[1], s, q[2]); s = fmaf(u[2], s, q[3]);
        s = fmaf(u[3], s, q[4]); s = fmaf(u[4], s, q[5]); s = fmaf(u[5], s, q[6]);
        s = fmaf(u[6], s, q[7]);
        SCAN_STEP(s, mf1,  DPP_SHR1, 0xF);
        SCAN_STEP(s, mf2,  DPP_SHR2, 0xF);
        SCAN_STEP(s, mf4,  DPP_SHR4, 0xF);
        SCAN_STEP(s, mf8,  DPP_SHR8, 0xF);
        SCAN_STEP(s, mf15, DPP_BC15, 0xA);
        SCAN_STEP(s, mf31, DPP_BC31, 0xC);
        if (Eend) atomAddF(pbr + ov[7], s);
        if (hasB) atomAddF(pbr + ov[0], t0);
        if (anyMid) {
            if (E[1]) atomAddF(pbr + ov[1], t1);
            if (E[2]) atomAddF(pbr + ov[2], t2);
            if (E[3]) atomAddF(pbr + ov[3], t3);
            if (E[4]) atomAddF(pbr + ov[4], t4);
            if (E[5]) atomAddF(pbr + ov[5], t5);
            if (E[6]) atomAddF(pbr + ov[6], t6);
        }
    };

    if (fast) {
        const float*  xb = x + (size_t)b0 * (size_t)n_in + e0;
        const size_t  rs = (size_t)n_in;
        const int nb4 = nrows >> 2;
        float4 ra0, ra1, rb0, rb1, rc0, rc1, rd0, rd1;
        if (nb4 > 0) {
            ra0 = ntload4(xb);              ra1 = ntload4(xb + 4);
            rb0 = ntload4(xb + rs);         rb1 = ntload4(xb + rs + 4);
            rc0 = ntload4(xb + 2 * rs);     rc1 = ntload4(xb + 2 * rs + 4);
            rd0 = ntload4(xb + 3 * rs);     rd1 = ntload4(xb + 3 * rs + 4);
        }
        for (int ib = 0; ib < nb4; ++ib) {
            float4 na0, na1, nb0, nb1, nc0, nc1, nd0, nd1;
            const bool more = (ib + 1) < nb4;
            if (more) {
                const float* nx = xb + (size_t)(4 * ib + 4) * rs;
                na0 = ntload4(nx);              na1 = ntload4(nx + 4);
                nb0 = ntload4(nx + rs);         nb1 = ntload4(nx + rs + 4);
                nc0 = ntload4(nx + 2 * rs);     nc1 = ntload4(nx + 2 * rs + 4);
                nd0 = ntload4(nx + 3 * rs);     nd1 = ntload4(nx + 3 * rs + 4);
            }
            {
                float q[8] = { ra0.x * w[0], ra0.y * w[1], ra0.z * w[2], ra0.w * w[3],
                               ra1.x * w[4], ra1.y * w[5], ra1.z * w[6], ra1.w * w[7] };
                processRow(q, pb);
            }
            {
                float q[8] = { rb0.x * w[0], rb0.y * w[1], rb0.z * w[2], rb0.w * w[3],
                               rb1.x * w[4], rb1.y * w[5], rb1.z * w[6], rb1.w * w[7] };
                processRow(q, pb + (size_t)n_out);
            }
            {
                float q[8] = { rc0.x * w[0], rc0.y * w[1], rc0.z * w[2], rc0.w * w[3],
                               rc1.x * w[4], rc1.y * w[5], rc1.z * w[6], rc1.w * w[7] };
                processRow(q, pb + 2 * (size_t)n_out);
            }
            {
                float q[8] = { rd0.x * w[0], rd0.y * w[1], rd0.z * w[2], rd0.w * w[3],
                               rd1.x * w[4], rd1.y * w[5], rd1.z * w[6], rd1.w * w[7] };
                processRow(q, pb + 3 * (size_t)n_out);
            }
            pb += 4 * (size_t)n_out;
            if (more) { ra0 = na0; ra1 = na1; rb0 = nb0; rb1 = nb1;
                        rc0 = nc0; rc1 = nc1; rd0 = nd0; rd1 = nd1; }
        }
        for (int i = nb4 * 4; i < nrows; ++i) {
            const float* nx = xb + (size_t)i * rs;
            float4 a0 = ntload4(nx);
            float4 a1 = ntload4(nx + 4);
            float q[8] = { a0.x * w[0], a0.y * w[1], a0.z * w[2], a0.w * w[3],
                           a1.x * w[4], a1.y * w[5], a1.z * w[6], a1.w * w[7] };
            processRow(q, pb);
            pb += (size_t)n_out;
        }
    } else {
        const float* xr = x + (size_t)b0 * (size_t)n_in;
        for (int i = 0; i < nrows; ++i) {
            float q[8];
            #pragma unroll
            for (int k = 0; k < 8; ++k) q[k] = xr[ix[k]] * w[k];
            processRow(q, pb);
            xr += (size_t)n_in; pb += (size_t)n_out;
        }
    }
}

__global__ __launch_bounds__(256)
void ld1d_finish_vec(float* __restrict__ out, const float* __restrict__ bias, int n_out4)
{
    const int o4 = blockIdx.x * 256 + threadIdx.x;
    if (o4 >= n_out4) return;
    const size_t flat = (size_t)blockIdx.y * (size_t)n_out4 * 4 + (size_t)o4 * 4;
    float4 v  = *reinterpret_cast<float4*>(out + flat);
    float4 bz = *reinterpret_cast<const float4*>(bias + (size_t)o4 * 4);
    v.x = tanhf(v.x + bz.x); v.y = tanhf(v.y + bz.y);
    v.z = tanhf(v.z + bz.z); v.w = tanhf(v.w + bz.w);
    *reinterpret_cast<float4*>(out + flat) = v;
}

__global__ __launch_bounds__(256)
void ld1d_finish_scalar(float* __restrict__ out, const float* __restrict__ bias,
                        int n_out, int ntot)
{
    int i = blockIdx.x * 256 + threadIdx.x;
    if (i >= ntot) return;
    int o = i % n_out;
    out[i] = tanhf(out[i] + bias[o]);
}

extern "C" void kernel_launch(void* const* d_in, const int* in_sizes, int n_in_arrs,
                              void* d_out, int out_size, void* d_ws, size_t ws_size,
                              hipStream_t stream)
{
    const float* x       = (const float*)d_in[0];
    const float* wgt     = (const float*)d_in[1];
    const float* bias    = (const float*)d_in[2];
    const int*   in_idx  = (const int*)d_in[3];
    const int*   out_idx = (const int*)d_in[4];
    float*       out     = (float*)d_out;

    const int nnz   = in_sizes[1];
    const int n_out = in_sizes[2];           // N_OUT * FILTERS(=1)
    const int batch = out_size / n_out;      // 64
    const int n_in  = in_sizes[0] / batch;   // 1,000,000

    // K0: zero the accumulator (= d_out)
    const int n4 = out_size / 4;
    hipLaunchKernelGGL(ld1d_zero, dim3((n4 + 255) / 256), dim3(256), 0, stream,
                       out, n4, out_size);

    // K1: 512-edge windows, DPP segmented scan, atomic emissions
    const int nwin = (nnz + EPW - 1) / EPW;
    const int wpw  = (batch + RPW - 1) / RPW;            // waves per window
    const long long totalWaves = (long long)nwin * wpw;
    const int ablocks = (int)((totalWaves + WPB - 1) / WPB);
    hipLaunchKernelGGL(ld1d_accum, dim3(ablocks), dim3(256), 0, stream,
                       x, wgt, in_idx, out_idx, out, n_in, nnz, n_out, batch, wpw);

    // K2: bias + tanh in place
    if ((n_out & 3) == 0) {
        const int n_out4 = n_out / 4;
        hipLaunchKernelGGL(ld1d_finish_vec,
                           dim3((n_out4 + 255) / 256, batch), dim3(256), 0, stream,
                           out, bias, n_out4);
    } else {
        hipLaunchKernelGGL(ld1d_finish_scalar,
                           dim3((out_size + 255) / 256), dim3(256), 0, stream,
                           out, bias, n_out, out_size);
    }
}

// Round 9
// 58.152 us; speedup vs baseline: 1.6453x; 1.2877x over previous
//
#include <hip/hip_runtime.h>
#include <cstdint>
#include <cstddef>

// LocallyDirected1D: y[b,o] = tanh( sum_{e: out_idx[e]==o} x[b, in_idx[e]] * w[e] + bias[o] )
// out_idx sorted ascending; in_idx == arange in practice (verified per window; wave-uniform
// clamped-gather fallback otherwise).
//
// R9 == R5 verbatim (proven 60.5 us): zero / accum / finish.
//  * EPW=512: each lane owns 8 contiguous edges. In-lane run sums via two 7-fma chains:
//      t_j (suffix, stops at first break after j)  -> head run t_0, mid runs t_j
//      s   (prefix, restarts after each break)     -> tail-run input for the wave scan
//    Wave-level masked Hillis-Steele DPP scan (6 steps).
//  * Register double-buffered prefetch: next 2-row batch's x loads issued before
//    processing the current batch (8 float4 in flight; VGPR stays under the 128 cliff —
//    R8's 16-in-flight variant regressed 24%, attributed to the occupancy cliff).
//  Emissions via fp32 agent-scope atomics into pre (=d_out, zeroed by K0); split emissions
//  across windows/lanes sum correctly. K2 applies bias+tanh in place.

constexpr int EPW = 512;   // edges per window (8 per lane)
constexpr int RPW = 16;    // batch rows per wave (4 waves share a window)
constexpr int WPB = 4;     // waves per block

#define DPP_SHR1 0x111
#define DPP_SHR2 0x112
#define DPP_SHR4 0x114
#define DPP_SHR8 0x118
#define DPP_BC15 0x142
#define DPP_BC31 0x143

#define SCAN_STEP(S, MF, CTRL, RM)                                                            \
    {                                                                                         \
        int _t = __builtin_amdgcn_update_dpp(0, __float_as_int(S), (CTRL), (RM), 0xF, true);  \
        (S) = fmaf((MF), __int_as_float(_t), (S));                                            \
    }

#define MAXS_STEP(R, CTRL, RM)                                                                \
    {                                                                                         \
        int _t = __builtin_amdgcn_update_dpp(0, (R), (CTRL), (RM), 0xF, true);                \
        (R) = max((R), _t);                                                                   \
    }

__device__ __forceinline__ void atomAddF(float* p, float v) {
    __hip_atomic_fetch_add(p, v, __ATOMIC_RELAXED, __HIP_MEMORY_SCOPE_AGENT);
}

__global__ __launch_bounds__(256)
void ld1d_zero(float* __restrict__ p, int n4, int ntot)
{
    int i = blockIdx.x * 256 + threadIdx.x;
    if (i < n4)
        *reinterpret_cast<float4*>(p + (size_t)i * 4) = make_float4(0.f, 0.f, 0.f, 0.f);
    if (blockIdx.x == 0 && threadIdx.x == 0)
        for (int k = n4 * 4; k < ntot; ++k) p[k] = 0.f;
}

__global__ __launch_bounds__(256)
void ld1d_accum(const float* __restrict__ x, const float* __restrict__ wgt,
                const int* __restrict__ in_idx, const int* __restrict__ out_idx,
                float* __restrict__ pre, int n_in, int nnz, int n_out, int batch, int wpw)
{
    const int lane = threadIdx.x & 63;
    const int gw   = blockIdx.x * WPB + (threadIdx.x >> 6);
    const int wid  = gw / wpw;
    const long long c0l = (long long)wid * EPW;
    if (c0l >= (long long)nnz) return;
    const int b0 = (gw - wid * wpw) * RPW;
    const int nrows = min(RPW, batch - b0);
    if (nrows <= 0) return;

    const int e0   = (int)c0l + lane * 8;
    const int last = nnz - 1;

    int   iv[8]; int ov[8]; float w[8];
    bool fok;
    if (e0 + 7 < nnz) {
        int4 i0 = *reinterpret_cast<const int4*>(in_idx + e0);
        int4 i1 = *reinterpret_cast<const int4*>(in_idx + e0 + 4);
        int4 o0 = *reinterpret_cast<const int4*>(out_idx + e0);
        int4 o1 = *reinterpret_cast<const int4*>(out_idx + e0 + 4);
        float4 w0 = *reinterpret_cast<const float4*>(wgt + e0);
        float4 w1 = *reinterpret_cast<const float4*>(wgt + e0 + 4);
        iv[0]=i0.x; iv[1]=i0.y; iv[2]=i0.z; iv[3]=i0.w; iv[4]=i1.x; iv[5]=i1.y; iv[6]=i1.z; iv[7]=i1.w;
        ov[0]=o0.x; ov[1]=o0.y; ov[2]=o0.z; ov[3]=o0.w; ov[4]=o1.x; ov[5]=o1.y; ov[6]=o1.z; ov[7]=o1.w;
        w[0]=w0.x; w[1]=w0.y; w[2]=w0.z; w[3]=w0.w; w[4]=w1.x; w[5]=w1.y; w[6]=w1.z; w[7]=w1.w;
        fok = true;
        #pragma unroll
        for (int k = 0; k < 8; ++k) fok = fok && (iv[k] == e0 + k);
    } else if (e0 < nnz) {
        #pragma unroll
        for (int k = 0; k < 8; ++k) {
            int a = min(e0 + k, last);
            iv[k] = in_idx[a]; ov[k] = out_idx[a];
            w[k]  = (e0 + k < nnz) ? wgt[a] : 0.f;
        }
        fok = false;
    } else {
        int o = out_idx[last];
        #pragma unroll
        for (int k = 0; k < 8; ++k) { iv[k] = 0; ov[k] = o; w[k] = 0.f; }
        fok = true;
    }
    const bool fast = (bool)__all((int)fok);

    // In-lane run structure (row-independent).
    bool bb[7]; float u[7];
    #pragma unroll
    for (int k = 0; k < 7; ++k) { bb[k] = (ov[k] != ov[k + 1]); u[k] = bb[k] ? 0.f : 1.f; }
    const bool hasB = bb[0] | bb[1] | bb[2] | bb[3] | bb[4] | bb[5] | bb[6];

    const int  pw   = __shfl_up(ov[7], 1);
    const bool cont = (lane > 0) && (ov[0] == pw);
    const bool fbrk = hasB || !cont;
    const int  fnext = __shfl_down((int)fbrk, 1);
    const bool Eend  = (lane == 63) || (fnext != 0);

    // Mid-run flags: run starts at j (bb[j-1]) and ends before e7 (a break in [j,6]).
    bool sfx[7];                       // sfx[j] = bb[j] | ... | bb[6]
    sfx[6] = bb[6];
    #pragma unroll
    for (int j = 5; j >= 1; --j) sfx[j] = bb[j] | sfx[j + 1];
    bool E[7];
    #pragma unroll
    for (int j = 1; j <= 6; ++j) E[j] = bb[j - 1] && sfx[j];
    const bool anyMid = (bool)__any((int)(E[1] | E[2] | E[3] | E[4] | E[5] | E[6]));

    // Run-start lane r -> per-step scan masks.
    int r = fbrk ? lane : 0;
    MAXS_STEP(r, DPP_SHR1, 0xF); MAXS_STEP(r, DPP_SHR2, 0xF);
    MAXS_STEP(r, DPP_SHR4, 0xF); MAXS_STEP(r, DPP_SHR8, 0xF);
    MAXS_STEP(r, DPP_BC15, 0xA); MAXS_STEP(r, DPP_BC31, 0xC);
    const float mf1  = (r <= lane - 1) ? 1.f : 0.f;
    const float mf2  = (r <= lane - 2) ? 1.f : 0.f;
    const float mf4  = (r <= lane - 4) ? 1.f : 0.f;
    const float mf8  = (r <= lane - 8) ? 1.f : 0.f;
    const float mf15 = (r <= (lane & ~15) - 1) ? 1.f : 0.f;
    const float mf31 = (r <= 31) ? 1.f : 0.f;

    // Clamped gather indices (slow path).
    const int nmax = n_in - 1;
    int ix[8];
    #pragma unroll
    for (int k = 0; k < 8; ++k) ix[k] = min(max(iv[k], 0), nmax);

    float* pb = pre + (size_t)b0 * (size_t)n_out;

    auto processRow = [&](const float q[8], float* pbr) {
        // suffix chains: t[j] = run sum starting at j (stops at first break)
        float t7 = q[7];
        float t6 = fmaf(u[6], t7, q[6]);
        float t5 = fmaf(u[5], t6, q[5]);
        float t4 = fmaf(u[4], t5, q[4]);
        float t3 = fmaf(u[3], t4, q[3]);
        float t2 = fmaf(u[2], t3, q[2]);
        float t1 = fmaf(u[1], t2, q[1]);
        float t0 = fmaf(u[0], t1, q[0]);
        // prefix chain: s = tail-run in-lane sum
        float s = q[0];
        s = fmaf(u[0], s, q[1]); s = fmaf(u[1], s, q[2]); s = fmaf(u[2], s, q[3]);
        s = fmaf(u[3], s, q[4]); s = fmaf(u[4], s, q[5]); s = fmaf(u[5], s, q[6]);
        s = fmaf(u[6], s, q[7]);
        // wave scan over tail sums
        SCAN_STEP(s, mf1,  DPP_SHR1, 0xF);
        SCAN_STEP(s, mf2,  DPP_SHR2, 0xF);
        SCAN_STEP(s, mf4,  DPP_SHR4, 0xF);
        SCAN_STEP(s, mf8,  DPP_SHR8, 0xF);
        SCAN_STEP(s, mf15, DPP_BC15, 0xA);
        SCAN_STEP(s, mf31, DPP_BC31, 0xC);
        if (Eend) atomAddF(pbr + ov[7], s);
        if (hasB) atomAddF(pbr + ov[0], t0);
        if (anyMid) {
            if (E[1]) atomAddF(pbr + ov[1], t1);
            if (E[2]) atomAddF(pbr + ov[2], t2);
            if (E[3]) atomAddF(pbr + ov[3], t3);
            if (E[4]) atomAddF(pbr + ov[4], t4);
            if (E[5]) atomAddF(pbr + ov[5], t5);
            if (E[6]) atomAddF(pbr + ov[6], t6);
        }
    };

    if (fast) {
        const float*  xb = x + (size_t)b0 * (size_t)n_in + e0;
        const size_t  rs = (size_t)n_in;
        const int nb2 = nrows >> 1;
        float4 ca0, ca1, cb0, cb1;
        if (nb2 > 0) {
            ca0 = *reinterpret_cast<const float4*>(xb);
            ca1 = *reinterpret_cast<const float4*>(xb + 4);
            cb0 = *reinterpret_cast<const float4*>(xb + rs);
            cb1 = *reinterpret_cast<const float4*>(xb + rs + 4);
        }
        for (int ib = 0; ib < nb2; ++ib) {
            float4 na0, na1, nb0, nb1;
            const bool more = (2 * ib + 2) < (nb2 << 1);
            if (more) {
                const float* nx = xb + (size_t)(2 * ib + 2) * rs;
                na0 = *reinterpret_cast<const float4*>(nx);
                na1 = *reinterpret_cast<const float4*>(nx + 4);
                nb0 = *reinterpret_cast<const float4*>(nx + rs);
                nb1 = *reinterpret_cast<const float4*>(nx + rs + 4);
            }
            {
                float q[8] = { ca0.x * w[0], ca0.y * w[1], ca0.z * w[2], ca0.w * w[3],
                               ca1.x * w[4], ca1.y * w[5], ca1.z * w[6], ca1.w * w[7] };
                processRow(q, pb);
            }
            {
                float q[8] = { cb0.x * w[0], cb0.y * w[1], cb0.z * w[2], cb0.w * w[3],
                               cb1.x * w[4], cb1.y * w[5], cb1.z * w[6], cb1.w * w[7] };
                processRow(q, pb + n_out);
            }
            pb += 2 * (size_t)n_out;
            if (more) { ca0 = na0; ca1 = na1; cb0 = nb0; cb1 = nb1; }
        }
        if (nrows & 1) {
            const float* nx = xb + (size_t)(nrows - 1) * rs;
            float4 a0 = *reinterpret_cast<const float4*>(nx);
            float4 a1 = *reinterpret_cast<const float4*>(nx + 4);
            float q[8] = { a0.x * w[0], a0.y * w[1], a0.z * w[2], a0.w * w[3],
                           a1.x * w[4], a1.y * w[5], a1.z * w[6], a1.w * w[7] };
            processRow(q, pb);
        }
    } else {
        const float* xr = x + (size_t)b0 * (size_t)n_in;
        for (int i = 0; i < nrows; ++i) {
            float q[8];
            #pragma unroll
            for (int k = 0; k < 8; ++k) q[k] = xr[ix[k]] * w[k];
            processRow(q, pb);
            xr += (size_t)n_in; pb += (size_t)n_out;
        }
    }
}

__global__ __launch_bounds__(256)
void ld1d_finish_vec(float* __restrict__ out, const float* __restrict__ bias, int n_out4)
{
    const int o4 = blockIdx.x * 256 + threadIdx.x;
    if (o4 >= n_out4) return;
    const size_t flat = (size_t)blockIdx.y * (size_t)n_out4 * 4 + (size_t)o4 * 4;
    float4 v  = *reinterpret_cast<float4*>(out + flat);
    float4 bz = *reinterpret_cast<const float4*>(bias + (size_t)o4 * 4);
    v.x = tanhf(v.x + bz.x); v.y = tanhf(v.y + bz.y);
    v.z = tanhf(v.z + bz.z); v.w = tanhf(v.w + bz.w);
    *reinterpret_cast<float4*>(out + flat) = v;
}

__global__ __launch_bounds__(256)
void ld1d_finish_scalar(float* __restrict__ out, const float* __restrict__ bias,
                        int n_out, int ntot)
{
    int i = blockIdx.x * 256 + threadIdx.x;
    if (i >= ntot) return;
    int o = i % n_out;
    out[i] = tanhf(out[i] + bias[o]);
}

extern "C" void kernel_launch(void* const* d_in, const int* in_sizes, int n_in_arrs,
                              void* d_out, int out_size, void* d_ws, size_t ws_size,
                              hipStream_t stream)
{
    const float* x       = (const float*)d_in[0];
    const float* wgt     = (const float*)d_in[1];
    const float* bias    = (const float*)d_in[2];
    const int*   in_idx  = (const int*)d_in[3];
    const int*   out_idx = (const int*)d_in[4];
    float*       out     = (float*)d_out;

    const int nnz   = in_sizes[1];
    const int n_out = in_sizes[2];           // N_OUT * FILTERS(=1)
    const int batch = out_size / n_out;      // 64
    const int n_in  = in_sizes[0] / batch;   // 1,000,000

    // K0: zero the accumulator (= d_out)
    const int n4 = out_size / 4;
    hipLaunchKernelGGL(ld1d_zero, dim3((n4 + 255) / 256), dim3(256), 0, stream,
                       out, n4, out_size);

    // K1: 512-edge windows, DPP segmented scan, atomic emissions
    const int nwin = (nnz + EPW - 1) / EPW;
    const int wpw  = (batch + RPW - 1) / RPW;            // waves per window
    const long long totalWaves = (long long)nwin * wpw;
    const int ablocks = (int)((totalWaves + WPB - 1) / WPB);
    hipLaunchKernelGGL(ld1d_accum, dim3(ablocks), dim3(256), 0, stream,
                       x, wgt, in_idx, out_idx, out, n_in, nnz, n_out, batch, wpw);

    // K2: bias + tanh in place
    if ((n_out & 3) == 0) {
        const int n_out4 = n_out / 4;
        hipLaunchKernelGGL(ld1d_finish_vec,
                           dim3((n_out4 + 255) / 256, batch), dim3(256), 0, stream,
                           out, bias, n_out4);
    } else {
        hipLaunchKernelGGL(ld1d_finish_scalar,
                           dim3((out_size + 255) / 256), dim3(256), 0, stream,
                           out, bias, n_out, out_size);
    }
}